// Round 1
// baseline (162.945 us; speedup 1.0000x reference)
//
#include <hip/hip_runtime.h>
#include <math.h>

// RWKV WKV forward, chunked parallel scan.
// B=8, T=2048, H=768 (fixed by setup_inputs). NC=32 chunks of L=64.
// d_ws layout: wa[B][NC][H], wb[B][NC][H], we[B][NC][H]  (3 * 196608 floats = 2.36 MB)

#define B_  8
#define T_  2048
#define H_  768
#define NC_ 32
#define L_  64

// ---------------- Phase 1: per-chunk local aggregates ----------------
// thread = one (b, chunk, h). Starting state (0,0,-inf), run L steps of the
// state recurrence only (no wkv output). Store (a,b,e).
__global__ __launch_bounds__(256) void wkv_phase1(
    const float* __restrict__ key, const float* __restrict__ val,
    const float* __restrict__ time_decay,
    float* __restrict__ wa, float* __restrict__ wb, float* __restrict__ we)
{
    const int h = blockIdx.x * 256 + threadIdx.x;   // H_/256 blocks in x
    const int c = blockIdx.y;
    const int b = blockIdx.z;

    const float w = -__expf(time_decay[h]);

    const size_t base = ((size_t)b * T_ + (size_t)c * L_) * H_ + h;
    const float* kp = key + base;
    const float* vp = val + base;

    float a = 0.f, bb = 0.f, e = -INFINITY;
#pragma unroll 4
    for (int t = 0; t < L_; ++t) {
        const float kt = kp[(size_t)t * H_];
        const float vt = vp[(size_t)t * H_];
        const float ew = e + w;
        const float m2 = fmaxf(ew, kt);
        const float s1 = __expf(ew - m2);
        const float s2 = __expf(kt - m2);
        a  = fmaf(s1, a,  s2 * vt);
        bb = fmaf(s1, bb, s2);
        e  = m2;
    }
    const size_t off = ((size_t)b * NC_ + c) * H_ + h;
    wa[off] = a; wb[off] = bb; we[off] = e;
}

// ---------------- Phase 2: sequential combine across chunks ----------------
// thread = one (b,h). Running state starts (0,0,-inf). For each chunk c:
// write the running (incoming) state into [b][c][h], then fold in chunk c's
// aggregate: state' = e^{w*L} * state + agg_c (stabilized).
__global__ __launch_bounds__(256) void wkv_phase2(
    float* __restrict__ wa, float* __restrict__ wb, float* __restrict__ we,
    const float* __restrict__ time_decay)
{
    const int idx = blockIdx.x * 256 + threadIdx.x;  // 0 .. B_*H_-1
    const int b = idx / H_;
    const int h = idx - b * H_;

    const float wL = -__expf(time_decay[h]) * (float)L_;

    float ra = 0.f, rb = 0.f, re = -INFINITY;

    // prefetch chunk 0
    size_t off = (size_t)b * NC_ * H_ + h;
    float ca = wa[off], cb = wb[off], ce = we[off];

#pragma unroll
    for (int c = 0; c < NC_; ++c) {
        const size_t noff = off + H_;
        float na = 0.f, nb = 0.f, ne = 0.f;
        if (c + 1 < NC_) {              // prefetch next chunk's aggregate
            na = wa[noff]; nb = wb[noff]; ne = we[noff];
        }
        // store incoming state for chunk c (in-place overwrite)
        wa[off] = ra; wb[off] = rb; we[off] = re;

        // combine: running <- e^{wL} * running + agg_c
        const float e1 = re + wL;
        const float m  = fmaxf(e1, ce);
        const float p  = __expf(e1 - m);
        const float q  = __expf(ce - m);
        ra = fmaf(ra, p, ca * q);
        rb = fmaf(rb, p, cb * q);
        re = m;

        ca = na; cb = nb; ce = ne;
        off = noff;
    }
}

// ---------------- Phase 3: replay each chunk from its incoming state ----------------
__global__ __launch_bounds__(256) void wkv_phase3(
    const float* __restrict__ key, const float* __restrict__ val,
    const float* __restrict__ time_decay, const float* __restrict__ time_first,
    const float* __restrict__ wa, const float* __restrict__ wb,
    const float* __restrict__ we, float* __restrict__ out)
{
    const int h = blockIdx.x * 256 + threadIdx.x;
    const int c = blockIdx.y;
    const int b = blockIdx.z;

    const float u = time_first[h];
    const float w = -__expf(time_decay[h]);

    const size_t soff = ((size_t)b * NC_ + c) * H_ + h;
    float a  = wa[soff];
    float bb = wb[soff];
    float e  = we[soff];

    const size_t base = ((size_t)b * T_ + (size_t)c * L_) * H_ + h;
    const float* kp = key + base;
    const float* vp = val + base;
    float*       op = out + base;

#pragma unroll 4
    for (int t = 0; t < L_; ++t) {
        const float kt = kp[(size_t)t * H_];
        const float vt = vp[(size_t)t * H_];

        // wkv output at this timestep (state BEFORE update)
        const float uk = u + kt;
        const float m1 = fmaxf(e, uk);
        const float wt = __expf(uk - m1);
        const float sc = __expf(e - m1);
        const float num = fmaf(a,  sc, wt * vt);
        const float den = fmaf(bb, sc, wt);
        op[(size_t)t * H_] = num / den;

        // state update
        const float ew = e + w;
        const float m2 = fmaxf(ew, kt);
        const float s1 = __expf(ew - m2);
        const float s2 = __expf(kt - m2);
        a  = fmaf(s1, a,  s2 * vt);
        bb = fmaf(s1, bb, s2);
        e  = m2;
    }
}

extern "C" void kernel_launch(void* const* d_in, const int* in_sizes, int n_in,
                              void* d_out, int out_size, void* d_ws, size_t ws_size,
                              hipStream_t stream) {
    const float* key = (const float*)d_in[0];
    const float* val = (const float*)d_in[1];
    const float* td  = (const float*)d_in[2];
    const float* tf  = (const float*)d_in[3];
    float* out = (float*)d_out;

    float* wa = (float*)d_ws;
    float* wb = wa + (size_t)B_ * NC_ * H_;
    float* we = wb + (size_t)B_ * NC_ * H_;

    dim3 blk(256);
    dim3 grid13(H_ / 256, NC_, B_);   // 3 x 32 x 8 = 768 blocks
    wkv_phase1<<<grid13, blk, 0, stream>>>(key, val, td, wa, wb, we);

    dim3 grid2((B_ * H_) / 256);      // 24 blocks
    wkv_phase2<<<grid2, blk, 0, stream>>>(wa, wb, we, td);

    wkv_phase3<<<grid13, blk, 0, stream>>>(key, val, td, tf, wa, wb, we, out);
}